// Round 6
// baseline (1677.986 us; speedup 1.0000x reference)
//
#include <hip/hip_runtime.h>
#include <math.h>

#define NN 128
#define BLK 512            // two matrices per block, 256 threads each
#define WSF (NN * 17)      // 2176 floats per overlay region

__device__ __forceinline__ float hsum4(float4 v) { return (v.x + v.y) + (v.z + v.w); }

__device__ __forceinline__ double waveRedD(double v) {
#pragma unroll
  for (int off = 32; off > 0; off >>= 1) v += __shfl_down(v, off, 64);
  return v;
}
__device__ __forceinline__ float waveRedF(float v) {
#pragma unroll
  for (int off = 32; off > 0; off >>= 1) v += __shfl_down(v, off, 64);
  return v;
}
__device__ __forceinline__ float getc(float4 a, int c) {
  return (c == 0) ? a.x : (c == 1) ? a.y : (c == 2) ? a.z : a.w;
}
// per-matrix block reduce over the matrix's 4 waves (t = tid within matrix)
__device__ __forceinline__ double blockReduceSumM(double v, double* red4, int t) {
  v = waveRedD(v);
  __syncthreads();
  if ((t & 63) == 0) red4[t >> 6] = v;
  __syncthreads();
  return (red4[0] + red4[1]) + (red4[2] + red4[3]);
}
__device__ __forceinline__ float startvec(int i, int k) {
  unsigned h = (unsigned)(i * 1664525 + k * 1013904223 + 12345);
  h ^= h >> 13; h *= 2654435761u; h ^= h >> 16;
  return ((float)(h & 0xFFFFFFu) * (1.0f / 16777216.0f)) - 0.5f;
}

extern "C" __global__ void __launch_bounds__(BLK, 4)
holo_kernel(const float* __restrict__ A, const float* __restrict__ F,
            const float* __restrict__ swg, const float* __restrict__ curv,
            const float* __restrict__ W1, const float* __restrict__ Bb1,
            const float* __restrict__ W2, const float* __restrict__ Bb2,
            const float* __restrict__ OW1, const float* __restrict__ OB1,
            const float* __restrict__ OW2, const float* __restrict__ OB2,
            float* __restrict__ out, int B)
{
  __shared__ __align__(16) float wsA[2 * WSF];
  __shared__ __align__(16) float wsB[2 * WSF];
  __shared__ unsigned swb_s[2 * 80];
  __shared__ double dd_s[2 * NN], ee_s[2 * NN], ee2_s[2 * NN];
  __shared__ float  tvecf_s[2 * NN];
  __shared__ double red_s[2 * 4], sc_s[2 * 8];
  __shared__ float  redupf_s[2 * 2], redutf_s[2 * 2], redsigf_s[2 * 2];
  __shared__ double lam_s[2 * 20], blo_s[2 * 17], bhi_s[2 * 17];
  __shared__ int    bcnt_s[2 * 119];
  __shared__ double ssv_s[2 * 16], dred_s[2 * 16];
  __shared__ float  msv_s[2 * 64], pool_s[2 * 16], zrow_s[2 * 16];

  const int  tid = threadIdx.x;
  const int  mid = tid >> 8;     // matrix within block
  const int  t   = tid & 255;    // thread within matrix
  const int  r   = t & 127;      // row owned
  const int  h   = t >> 7;       // column half (cols 64h..64h+63)
  const int  lane = t & 63;
  const int  widm = t >> 6;      // wave index within matrix (0..3)

  // per-matrix pointers
  float*  wsAm = wsA + mid * WSF;
  float*  wsBm = wsB + mid * WSF;
  unsigned* swb = swb_s + mid * 80;
  double* dd  = dd_s  + mid * NN;
  double* ee  = ee_s  + mid * NN;
  double* ee2 = ee2_s + mid * NN;
  float*  tvecf = tvecf_s + mid * NN;
  double* red = red_s + mid * 4;
  double* sc  = sc_s  + mid * 8;
  float*  redupf  = redupf_s  + mid * 2;
  float*  redutf  = redutf_s  + mid * 2;
  float*  redsigf = redsigf_s + mid * 2;
  double* lam = lam_s + mid * 20;
  double* blo = blo_s + mid * 17;
  double* bhi = bhi_s + mid * 17;
  int*    bcnt = bcnt_s + mid * 119;
  double* ssv  = ssv_s  + mid * 16;
  double* dred = dred_s + mid * 16;
  float*  msv  = msv_s  + mid * 64;
  float*  pool = pool_s + mid * 16;
  float*  zrow = zrow_s + mid * 16;

  double* dscr  = (double*)wsAm;       // [256] (init only)
  float* svec   = wsAm + 512;
  float* invdeg = wsAm + 640;
  float* gvv    = wsAm + 768;
  float* cw     = wsAm + 896;
  float* ubuf   = wsAm + 1024;
  float* pbuf   = wsAm + 1152;
  float* colk   = wsAm + 1280;
  float* byv    = wsAm;                // [128*17] after Householder
  float* fscr   = wsBm;                // [256] during Householder
  float* sA     = wsBm;                // [128*17] invit LU store
  float* comb   = wsBm;                // [128] MLP
  float* hbuf   = wsBm + 128;

  const long bm = 2L * blockIdx.x + mid;              // global matrix index
  const long bc = (bm < B) ? bm : (long)(B - 1);      // clamped for loads
  const float* Ab = A + bc * (long)(NN * NN);
  const float* Fb = F + bc * (long)(NN * 64);

  // ---------------- load A: each thread owns half a row in registers ----------------
  float4 areg[16];
  {
    const float4* Arow = reinterpret_cast<const float4*>(Ab + (long)r * NN) + 16 * h;
#pragma unroll
    for (int uu = 0; uu < 16; ++uu) areg[uu] = Arow[uu];
  }
  if (t == 0) {
    const float a0 = swg[0], a1 = swg[1], a2 = swg[2];
    const float mx = fmaxf(a0, fmaxf(a1, a2));
    const float e0 = expf(a0 - mx), e1 = expf(a1 - mx), e2v = expf(a2 - mx);
    const float s = e0 + e1 + e2v;
    sc[0] = (double)(e0 / s); sc[1] = (double)(e1 / s); sc[2] = (double)(e2v / s);
  }
  // ---------------- degrees ----------------
  {
    float4 s4 = make_float4(0.f, 0.f, 0.f, 0.f);
#pragma unroll
    for (int uu = 0; uu < 16; ++uu) {
      s4.x += areg[uu].x; s4.y += areg[uu].y; s4.z += areg[uu].z; s4.w += areg[uu].w;
    }
    dscr[t] = (double)hsum4(s4);
  }
  __syncthreads();
  if (t < NN) {
    const double dg = dscr[t] + dscr[t + NN] + 1e-8;
    invdeg[t] = (float)(1.0 / dg);
    svec[t]   = (float)(1.0 / sqrt(dg));
  }
  __syncthreads();
  // g = R^T 1 (A symmetric: row dot invdeg)
  {
    const float4* iv4 = (const float4*)invdeg;
    float4 acc = make_float4(0.f, 0.f, 0.f, 0.f);
#pragma unroll
    for (int uu = 0; uu < 16; ++uu) {
      const float4 a = areg[uu], w = iv4[16 * h + uu];
      acc.x = fmaf(a.x, w.x, acc.x); acc.y = fmaf(a.y, w.y, acc.y);
      acc.z = fmaf(a.z, w.z, acc.z); acc.w = fmaf(a.w, w.w, acc.w);
    }
    fscr[t] = hsum4(acc);
  }
  __syncthreads();
  if (t < NN) {
    const float gv = fscr[t] + fscr[t + NN];
    gvv[t] = gv;
    ubuf[t] = gv * invdeg[t];
  }
  __syncthreads();
  // hv = R^T g
  {
    const float4* ub4 = (const float4*)ubuf;
    float4 acc = make_float4(0.f, 0.f, 0.f, 0.f);
#pragma unroll
    for (int uu = 0; uu < 16; ++uu) {
      const float4 a = areg[uu], w = ub4[16 * h + uu];
      acc.x = fmaf(a.x, w.x, acc.x); acc.y = fmaf(a.y, w.y, acc.y);
      acc.z = fmaf(a.z, w.z, acc.z); acc.w = fmaf(a.w, w.w, acc.w);
    }
    fscr[t] = hsum4(acc);
  }
  __syncthreads();
  if (t < NN) {
    const float hv = fscr[t] + fscr[t + NN];
    cw[t] = ((float)sc[0] + (float)sc[1] * gvv[t] + (float)sc[2] * hv) * (1.0f / NN);
  }
  __syncthreads();
  // ms[d] = sum_n cw[n] F[n][d]
  {
    const int d = t & 63, qt = t >> 6;
    float acc = 0.0f;
    const float* fb = Fb + qt * 32 * 64;
    for (int n = 0; n < 32; ++n) acc = fmaf(cw[qt * 32 + n], fb[n * 64 + d], acc);
    fscr[t] = acc;
  }
  __syncthreads();
  if (t < 64) msv[t] = (fscr[t] + fscr[64 + t]) + (fscr[128 + t] + fscr[192 + t]);

  // ---------------- L = I - D^-1/2 A D^-1/2 (registers) ----------------
  {
    const float sr = svec[r];
    const float4* sv4p = (const float4*)svec;
#pragma unroll
    for (int uu = 0; uu < 16; ++uu) {
      const float4 sv = sv4p[16 * h + uu];
      float4 a = areg[uu];
      a.x = -a.x * sr * sv.x; a.y = -a.y * sr * sv.y;
      a.z = -a.z * sr * sv.z; a.w = -a.w * sr * sv.w;
      areg[uu] = a;
    }
    if ((r >> 6) == h) {
      const int cl = r & 63, du = cl >> 2, dc = cl & 3;
#pragma unroll
      for (int uu = 0; uu < 16; ++uu) if (uu == du) {
        float4 a = areg[uu];
        a.x += (dc == 0) ? 1.f : 0.f; a.y += (dc == 1) ? 1.f : 0.f;
        a.z += (dc == 2) ? 1.f : 0.f; a.w += (dc == 3) ? 1.f : 0.f;
        areg[uu] = a;
      }
    }
  }
  // ---------------- prologue: column 0 extract + sigma + tvec init ----------------
  if (t < NN) tvecf[t] = 1.0f;
  if (h == 0) {
    const float v0 = areg[0].x;
    colk[r] = v0;
    if (r == 0) dd[0] = (double)v0;
    const float s = waveRedF((r >= 2) ? v0 * v0 : 0.f);
    if (lane == 0) redsigf[widm] = s;
  }
  __syncthreads();

  // ---------------- Householder: 4 barriers / iteration ----------------
  for (int k = 0; k < NN - 2; ++k) {
    // redundant scalar head (all threads of this matrix identical)
    const float sigma  = redsigf[0] + redsigf[1];
    const float alphaf = colk[k + 1];
    double betad; float tauf, sclf;
    if (sigma <= 0.f) { betad = (double)alphaf; tauf = 0.f; sclf = 0.f; }
    else {
      betad = -copysign(sqrt((double)alphaf * (double)alphaf + (double)sigma), (double)alphaf);
      const float betaf = (float)betad;
      tauf = (betaf - alphaf) / betaf;
      sclf = 1.0f / (alphaf - betaf);
    }
    if (t == 0) ee[k] = betad;
    if (h == 0) ubuf[r] = (r <= k) ? 0.f : (r == k + 1) ? 1.f : colk[r] * sclf;
    __syncthreads();                                   // A
    // matvec partials (registers x broadcast u), wave-level guards only
    {
      float4 acc = make_float4(0.f, 0.f, 0.f, 0.f);
      if (r >= k + 1 && 64 * h + 63 >= k + 1 && tauf != 0.f) {
        const float4* ub4 = (const float4*)ubuf;
#pragma unroll
        for (int uu = 0; uu < 16; ++uu) {
          const float4 a = areg[uu], u4 = ub4[16 * h + uu];
          acc.x = fmaf(a.x, u4.x, acc.x); acc.y = fmaf(a.y, u4.y, acc.y);
          acc.z = fmaf(a.z, u4.z, acc.z); acc.w = fmaf(a.w, u4.w, acc.w);
        }
      }
      fscr[t] = hsum4(acc);
    }
    __syncthreads();                                   // B
    // p = tau*A*u; float reduces of u.p and u.t (matrix waves 0,1)
    if (h == 0) {
      const float p = tauf * (fscr[r] + fscr[r + NN]);
      pbuf[r] = p;
      const float uv = ubuf[r];
      const float s1 = waveRedF(uv * p);
      const float s2 = waveRedF(uv * tvecf[r]);
      if (lane == 0) { redupf[widm] = s1; redutf[widm] = s2; }
    }
    __syncthreads();                                   // C
    // rank-2 update + tvec update + next-column extraction
    {
      const float K   = 0.5f * tauf * (redupf[0] + redupf[1]);
      const float tut = tauf * (redutf[0] + redutf[1]);
      if (r >= k + 1) {
        const float ur = ubuf[r];
        const float qr = fmaf(-K, ur, pbuf[r]);
        if (64 * h + 63 >= k + 1) {
          const float4* ub4 = (const float4*)ubuf;
          const float4* pb4 = (const float4*)pbuf;
#pragma unroll
          for (int uu = 0; uu < 16; ++uu) {
            const float4 u4 = ub4[16 * h + uu], p4 = pb4[16 * h + uu];
            float4 a = areg[uu];
            const float qx = fmaf(-K, u4.x, p4.x);
            const float qy = fmaf(-K, u4.y, p4.y);
            const float qz = fmaf(-K, u4.z, p4.z);
            const float qw = fmaf(-K, u4.w, p4.w);
            a.x -= ur * qx + qr * u4.x;
            a.y -= ur * qy + qr * u4.y;
            a.z -= ur * qz + qr * u4.z;
            a.w -= ur * qw + qr * u4.w;
            areg[uu] = a;
          }
        }
        if (h == 0) tvecf[r] -= tut * ubuf[r];
      }
      const int hstar = (k + 1) >> 6;                  // wave-uniform
      if (h == hstar) {
        float sigp = 0.0f;
        if (r >= k + 1) {
          const int cl = (k + 1) - 64 * hstar, du = cl >> 2, dc = cl & 3;
          float val = 0.f;
#pragma unroll
          for (int uu = 0; uu < 16; ++uu) if (uu == du) val = getc(areg[uu], dc);
          if (r == k + 1) dd[k + 1] = (double)val;
          else {
            colk[r] = val;
            if (r >= k + 3) sigp = val * val;
          }
        }
        const float s = waveRedF(sigp);
        if (lane == 0) redsigf[widm & 1] = s;
      }
    }
    __syncthreads();                                   // D
  }
  if (t == 0)   ee[NN - 2] = (double)colk[NN - 1];
  if (t == 255) dd[NN - 1] = (double)areg[15].w;       // r=127,h=1: col 127
  __syncthreads();

  // ---------------- bisection (multisection x7, 11 rounds) ----------------
  if (t < NN - 1) ee2[t] = ee[t] * ee[t];
  if (t == 0) {
    double lo = 1e300, hi = -1e300;
    for (int i = 0; i < NN; ++i) {
      const double rr = ((i > 0) ? fabs(ee[i - 1]) : 0.0) + ((i < NN - 1) ? fabs(ee[i]) : 0.0);
      lo = fmin(lo, dd[i] - rr);
      hi = fmax(hi, dd[i] + rr);
    }
    sc[4] = lo - 1e-6; sc[5] = hi + 1e-6;
  }
  __syncthreads();
  if (t < 17) { blo[t] = sc[4]; bhi[t] = sc[5]; }
  __syncthreads();
  for (int round = 0; round < 11; ++round) {
    if (t < 119) {
      const int ke = t / 7, j = t % 7;
      const double lo = blo[ke], hi = bhi[ke];
      const double x = lo + (hi - lo) * ((double)(j + 1) * 0.125);
      int cnt = 0;
      double pm = 1.0, p = dd[0] - x;
      if (p < 0.0) cnt++;
      for (int i = 1; i < NN; ++i) {
        const double pn = (dd[i] - x) * p - ee2[i - 1] * pm;
        pm = p; p = pn;
        if ((p < 0.0) != (pm < 0.0)) cnt++;
        const double ap = fabs(p);
        if (ap > 1e100)                   { p *= 1e-100; pm *= 1e-100; }
        else if (ap < 1e-100 && ap > 0.0) { p *= 1e100;  pm *= 1e100; }
      }
      bcnt[t] = cnt;
    }
    __syncthreads();
    if (t < 17) {
      const double lo = blo[t], hi = bhi[t];
      const double w8 = (hi - lo) * 0.125;
      double nlo = lo, nhi = hi;
      for (int jj = 0; jj < 7; ++jj) {
        const double x = lo + w8 * (double)(jj + 1);
        if (bcnt[t * 7 + jj] <= t) nlo = x; else { nhi = x; break; }
      }
      blo[t] = nlo; bhi[t] = nhi;
    }
    __syncthreads();
  }
  if (t < 17) lam[t] = 0.5 * (blo[t] + bhi[t]);
  __syncthreads();

  // ---------------- inverse iteration on T (matrix lanes 0..15), compressed LU ----------------
  if (t < 16) {
    const double lk = lam[t + 1];
    for (int it = 0; it < 2; ++it) {
      float beta = (float)(dd[0] - lk);
      float gam  = (float)ee[0];
      float rr   = (it == 0) ? startvec(0, t) : byv[0 * 17 + t];
      unsigned bw = 0;
      for (int i = 1; i < NN; ++i) {
        const int j = i - 1;
        const float ai = (float)ee[i - 1];
        const float bi = (float)(dd[i] - lk);
        const float ci = (i < NN - 1) ? (float)ee[i] : 0.0f;
        const float ri = (it == 0) ? startvec(i, t) : byv[i * 17 + t];
        if (fabsf(beta) >= fabsf(ai)) {
          float piv = (beta == 0.0f) ? 1e-25f : beta;
          const float mm = ai / piv;
          sA [j * 17 + t] = piv;
          byv[j * 17 + t] = rr;
          beta = bi - mm * gam;  gam = ci;  rr = ri - mm * rr;
        } else {
          const float mm = beta / ai;
          sA [j * 17 + t] = mm;
          byv[j * 17 + t] = ri;
          beta = gam - mm * bi;  gam = -mm * ci;  rr = rr - mm * ri;
          bw |= 1u << (j & 31);
        }
        if ((j & 31) == 31) { swb[t * 5 + (j >> 5)] = bw; bw = 0; }
      }
      if (beta == 0.0f) beta = 1e-25f;
      sA [127 * 17 + t] = beta;
      byv[127 * 17 + t] = rr;
      swb[t * 5 + 3] = bw;
      float y1 = 0.0f, y2 = 0.0f;
      for (int j = NN - 1; j >= 0; --j) {
        const bool sj = (swb[t * 5 + (j >> 5)] >> (j & 31)) & 1;
        const bool sjm1 = (j > 0) ? ((swb[t * 5 + ((j - 1) >> 5)] >> ((j - 1) & 31)) & 1) : false;
        float u0, u1, u2;
        if (sj) {
          u0 = (float)ee[j];
          u1 = (float)(dd[j + 1] - lk);
          u2 = (j < NN - 2) ? (float)ee[j + 1] : 0.0f;
        } else {
          u0 = sA[j * 17 + t];
          const float ej = (j < NN - 1) ? (float)ee[j] : 0.0f;
          u1 = sjm1 ? (-sA[(j - 1) * 17 + t] * ej) : ej;
          u2 = 0.0f;
        }
        const float yy = (byv[j * 17 + t] - u1 * y1 - u2 * y2) / u0;
        byv[j * 17 + t] = yy;
        y2 = y1; y1 = yy;
      }
      double nrm = 0.0;
      for (int i = 0; i < NN; ++i) { const double v = (double)byv[i * 17 + t]; nrm += v * v; }
      const double inv = 1.0 / sqrt(nrm);
      for (int i = 0; i < NN; ++i) byv[i * 17 + t] = (float)((double)byv[i * 17 + t] * inv);
    }
  }
  __syncthreads();

  // ---------------- MGS ----------------
  for (int kk = 1; kk < 16; ++kk) {
    const int j = t >> 3, s8 = t & 7;
    double part = 0.0;
    if (j < kk)
      for (int i = s8 * 16; i < s8 * 16 + 16; ++i)
        part += (double)byv[i * 17 + j] * (double)byv[i * 17 + kk];
    for (int off = 4; off > 0; off >>= 1) part += __shfl_down(part, off, 8);
    __syncthreads();
    if (s8 == 0 && j < kk) dred[j] = part;
    __syncthreads();
    if (t < NN) {
      double acc = (double)byv[t * 17 + kk];
      for (int j2 = 0; j2 < kk; ++j2) acc -= dred[j2] * (double)byv[t * 17 + j2];
      byv[t * 17 + kk] = (float)acc;
    }
    __syncthreads();
    double p2 = 0.0;
    if (t < NN) { const double v = (double)byv[t * 17 + kk]; p2 = v * v; }
    const double n2 = blockReduceSumM(p2, red, t);
    if (t < NN) byv[t * 17 + kk] = (float)((double)byv[t * 17 + kk] / sqrt(n2));
    __syncthreads();
  }

  // ---------------- s_k = t . y_k ; pooled ----------------
  if (t < NN) {
    const int j = t >> 3, s8 = t & 7;
    double part = 0.0;
    for (int i = s8 * 16; i < s8 * 16 + 16; ++i)
      part += (double)tvecf[i] * (double)byv[i * 17 + j];
    for (int off = 4; off > 0; off >>= 1) part += __shfl_down(part, off, 8);
    if (s8 == 0) ssv[j] = part;
  }
  __syncthreads();
  if (t == 0) {
    float lv[16], ev[16];
    float mx = -1e30f;
    for (int i = 0; i < 16; ++i) { lv[i] = (float)lam[i + 1]; mx = fmaxf(mx, -lv[i]); }
    float se = 0.0f;
    for (int i = 0; i < 16; ++i) { ev[i] = expf(-lv[i] - mx); se += ev[i]; }
    for (int i = 0; i < 16; ++i) pool[i] = (ev[i] / se) * (float)ssv[i];
  }
  __syncthreads();

  // ---------------- MLPs + outputs ----------------
  if (t < NN) {
    float acc = Bb1[t];
    for (int i = 0; i < 16; ++i) acc = fmaf(pool[i], W1[i * 128 + t], acc);
    hbuf[t] = fmaxf(acc, 0.0f);
  }
  __syncthreads();
  if (t < 64) {
    float acc = Bb2[t];
    for (int i = 0; i < 128; ++i) acc = fmaf(hbuf[i], W2[i * 64 + t], acc);
    comb[t] = acc;                       // spectral
  } else if (t < NN) {
    comb[t] = msv[t - 64];               // ms
  }
  __syncthreads();
  if (t < NN) {
    float acc = OB1[t];
    for (int i = 0; i < 128; ++i) acc = fmaf(comb[i], OW1[i * 128 + t], acc);
    hbuf[t] = fmaxf(acc, 0.0f);
  }
  __syncthreads();
  if (t < 16) {
    float acc = OB2[t];
    for (int i = 0; i < 128; ++i) acc = fmaf(hbuf[i], OW2[i * 16 + t], acc);
    zrow[t] = acc;
  }
  __syncthreads();

  const long zeoff = (long)B * 16;
  const long spoff = (long)B * 32;
  const long svoff = (long)B * 32 + (long)B * 64;
  const long coff  = svoff + (long)B * 16;

  if (t == 0) {
    const float c = 1.0f / (1.0f + expf(-curv[0]));
    float nrm = 0.0f;
    for (int i = 0; i < 16; ++i) nrm += zrow[i] * zrow[i];
    nrm = sqrtf(nrm);
    const float max_r = 0.95f / sqrtf(c);
    sc[3] = (double)fminf(1.0f, max_r / (nrm + 1e-12f));
    if (bm == 0) out[coff] = c;
  }
  __syncthreads();
  if (bm < B) {
    if (t < 16) {
      const float fac = (float)sc[3];
      out[bm * 16 + t]          = zrow[t] * fac;       // z
      out[zeoff + bm * 16 + t]  = zrow[t];             // z_euclidean
      out[svoff + bm * 16 + t]  = (float)lam[t + 1];   // sel_vals
    }
    if (t < 64) out[spoff + bm * 64 + t] = comb[t];    // spectral
  }
}

extern "C" void kernel_launch(void* const* d_in, const int* in_sizes, int n_in,
                              void* d_out, int out_size, void* d_ws, size_t ws_size,
                              hipStream_t stream) {
  const float* A    = (const float*)d_in[0];
  const float* F    = (const float*)d_in[1];
  const float* swg  = (const float*)d_in[2];
  const float* curv = (const float*)d_in[3];
  const float* W1   = (const float*)d_in[4];
  const float* Bb1  = (const float*)d_in[5];
  const float* W2   = (const float*)d_in[6];
  const float* Bb2  = (const float*)d_in[7];
  const float* OW1  = (const float*)d_in[8];
  const float* OB1  = (const float*)d_in[9];
  const float* OW2  = (const float*)d_in[10];
  const float* OB2  = (const float*)d_in[11];
  float* out = (float*)d_out;
  const int B = in_sizes[0] / (128 * 128);

  holo_kernel<<<dim3((B + 1) / 2), dim3(BLK), 0, stream>>>(
      A, F, swg, curv, W1, Bb1, W2, Bb2, OW1, OB1, OW2, OB2, out, B);
}